// Round 2
// baseline (751062.842 us; speedup 1.0000x reference)
//
#include <hip/hip_runtime.h>

typedef unsigned short ushort;
typedef unsigned int uint32;
typedef __attribute__((ext_vector_type(8))) short bf16x8;
typedef __attribute__((ext_vector_type(4))) float f32x4;

#define BATCH 16
#define TT 2048
#define HID 256

__device__ __forceinline__ ushort f2bf(float f) {
  union { float f; uint32 u; } v; v.f = f;
  uint32 r = v.u + 0x7FFFu + ((v.u >> 16) & 1u);
  return (ushort)(r >> 16);
}
__device__ __forceinline__ float bf2f(ushort u) {
  union { uint32 u; float f; } v; v.u = ((uint32)u) << 16; return v.f;
}
__device__ __forceinline__ float sigm(float x) { return 1.0f / (1.0f + __expf(-x)); }
__device__ __forceinline__ float tanh_fast(float x) { return 1.0f - 2.0f / (__expf(2.0f * x) + 1.0f); }

// ---------------- prep: casts + weight concat + bias sums ----------------
__global__ void prep_kernel(
    const float* __restrict__ x,
    const float* __restrict__ dWih_f, const float* __restrict__ dWih_b,
    const float* __restrict__ l0Wih_f, const float* __restrict__ l0Wih_b,
    const float* __restrict__ l1Wih_f, const float* __restrict__ l1Wih_b,
    const float* __restrict__ dbih_f, const float* __restrict__ dbhh_f,
    const float* __restrict__ dbih_b, const float* __restrict__ dbhh_b,
    const float* __restrict__ l0bih_f, const float* __restrict__ l0bhh_f,
    const float* __restrict__ l0bih_b, const float* __restrict__ l0bhh_b,
    const float* __restrict__ l1bih_f, const float* __restrict__ l1bhh_f,
    const float* __restrict__ l1bih_b, const float* __restrict__ l1bhh_b,
    ushort* __restrict__ xbf, ushort* __restrict__ wA, ushort* __restrict__ wB,
    ushort* __restrict__ wC, float* __restrict__ biasA, float* __restrict__ biasB,
    float* __restrict__ biasC)
{
  int g = blockIdx.x * blockDim.x + threadIdx.x;
  int str = gridDim.x * blockDim.x;
  for (int i = g; i < (BATCH * TT * 256) / 4; i += str) {
    float4 v = ((const float4*)x)[i];
    ushort4 o; o.x = f2bf(v.x); o.y = f2bf(v.y); o.z = f2bf(v.z); o.w = f2bf(v.w);
    ((ushort4*)xbf)[i] = o;
  }
  for (int i = g; i < 2048 * 256; i += str)
    wA[i] = f2bf(i < 1024 * 256 ? dWih_f[i] : dWih_b[i - 1024 * 256]);
  for (int i = g; i < 2048 * 256; i += str)
    wB[i] = f2bf(i < 1024 * 256 ? l0Wih_f[i] : l0Wih_b[i - 1024 * 256]);
  for (int i = g; i < 2048 * 512; i += str)
    wC[i] = f2bf(i < 1024 * 512 ? l1Wih_f[i] : l1Wih_b[i - 1024 * 512]);
  for (int i = g; i < 2048; i += str) {
    biasA[i] = i < 1024 ? dbih_f[i] + dbhh_f[i] : dbih_b[i - 1024] + dbhh_b[i - 1024];
    biasB[i] = i < 1024 ? l0bih_f[i] + l0bhh_f[i] : l0bih_b[i - 1024] + l0bhh_b[i - 1024];
    biasC[i] = i < 1024 ? l1bih_f[i] + l1bhh_f[i] : l1bih_b[i - 1024] + l1bhh_b[i - 1024];
  }
}

// ---------------- GEMM: xp = A[32768,K] * B[2048,K]^T + bias, out bf16 ----------------
__global__ __launch_bounds__(256) void gemm_xp(
    const ushort* __restrict__ A, const ushort* __restrict__ B, int K,
    const float* __restrict__ bias, ushort* __restrict__ xp)
{
  __shared__ __align__(16) ushort lA[128 * 64];
  __shared__ __align__(16) ushort lB[128 * 64];
  const int tid = threadIdx.x;
  const int lane = tid & 63, wv = tid >> 6;
  const int lo = lane & 15, hi = lane >> 4;
  const int wr = wv >> 1, wc = wv & 1;
  const int bm = blockIdx.y * 128, bn = blockIdx.x * 128;

  f32x4 acc[4][4] = {};

  const int nk = K >> 6;
  for (int kt = 0; kt < nk; ++kt) {
    uint4 ra[4], rb[4];
#pragma unroll
    for (int i = 0; i < 4; ++i) {
      int slot = i * 256 + tid;
      int r = slot >> 3, c8 = slot & 7;
      ra[i] = *(const uint4*)(A + (size_t)(bm + r) * K + kt * 64 + c8 * 8);
      rb[i] = *(const uint4*)(B + (size_t)(bn + r) * K + kt * 64 + c8 * 8);
    }
    __syncthreads();
#pragma unroll
    for (int i = 0; i < 4; ++i) {
      int slot = i * 256 + tid;
      int r = slot >> 3, c8 = slot & 7;
      int boff = r * 128 + ((c8 ^ (r & 7)) << 4);
      *(uint4*)((char*)lA + boff) = ra[i];
      *(uint4*)((char*)lB + boff) = rb[i];
    }
    __syncthreads();
#pragma unroll
    for (int kk = 0; kk < 2; ++kk) {
      bf16x8 fa[4], fb[4];
#pragma unroll
      for (int mt = 0; mt < 4; ++mt) {
        int r = wr * 64 + mt * 16 + lo;
        int c8 = kk * 4 + hi;
        fa[mt] = *(const bf16x8*)((const char*)lA + r * 128 + ((c8 ^ (r & 7)) << 4));
      }
#pragma unroll
      for (int nt = 0; nt < 4; ++nt) {
        int r = wc * 64 + nt * 16 + lo;
        int c8 = kk * 4 + hi;
        fb[nt] = *(const bf16x8*)((const char*)lB + r * 128 + ((c8 ^ (r & 7)) << 4));
      }
#pragma unroll
      for (int mt = 0; mt < 4; ++mt)
#pragma unroll
        for (int nt = 0; nt < 4; ++nt)
          acc[mt][nt] = __builtin_amdgcn_mfma_f32_16x16x32_bf16(fa[mt], fb[nt], acc[mt][nt], 0, 0, 0);
    }
  }
#pragma unroll
  for (int nt = 0; nt < 4; ++nt) {
    int n = bn + wc * 64 + nt * 16 + lo;
    float bv = bias[n];
#pragma unroll
    for (int mt = 0; mt < 4; ++mt) {
#pragma unroll
      for (int r = 0; r < 4; ++r) {
        float val = acc[mt][nt][r] + bv;
        uint32 h16 = f2bf(val);
        uint32 p16 = (uint32)__shfl_xor((int)h16, 1);
        if (!(lo & 1)) {
          int m = bm + wr * 64 + mt * 16 + hi * 4 + r;
          size_t dst = (size_t)(n >> 10) * ((size_t)BATCH * TT * 1024) + (size_t)m * 1024 + (n & 1023);
          *(uint32*)(xp + dst) = h16 | (p16 << 16);
        }
      }
    }
  }
}

// ---------------- sequential LSTM scan, v2 ----------------
// grid = 4 blocks: dir(2) x half(2). 512 thr = 8 waves (2/SIMD).
// Each WG owns 128 hidden units; weights register-resident.
// Per step: own h half via LDS (swizzled), partner half via agent atomics.
// Sync: one release-store flag per WG (own cacheline), wave0-only polling.
template <int MODE>
__global__ __launch_bounds__(512, 2) void scan2(
    const ushort* __restrict__ xp,
    const float* __restrict__ WhhF, const float* __restrict__ WhhB,
    const float* __restrict__ cwF, const float* __restrict__ cwB,
    const float* __restrict__ cbF, const float* __restrict__ cbB,
    float* __restrict__ coef,             // [2 dir][TT][16] fp32, scan-step indexed
    ushort* __restrict__ hstage,          // [2 dir][2 buf][16][256] bf16
    uint32* __restrict__ flags,           // [2dir*2wg] stride 32 uints
    ushort* __restrict__ outBf, float* __restrict__ outF32)
{
  const int tid = threadIdx.x;
  const int lane = tid & 63, wv = tid >> 6;
  const int lo = lane & 15, hi = lane >> 4;
  const int dir = blockIdx.x >> 1, w = blockIdx.x & 1;

  __shared__ __align__(16) ushort ldsH[2][16 * 128];  // [buf][b][128 units], XOR-swizzled
  __shared__ float ldsCW[256];

  for (int i = tid; i < 2 * 16 * 128 / 2; i += 512) ((uint32*)ldsH)[i] = 0;
  if (MODE == 0 && tid < 256) ldsCW[tid] = (dir ? cwB : cwF)[tid];
  __syncthreads();

  const ushort* xpD = xp + (size_t)dir * ((size_t)BATCH * TT * 1024);
  const float* Whh = dir ? WhhB : WhhF;
  ushort* hst = hstage + dir * (2 * BATCH * HID);
  uint32* myFlag = flags + (dir * 2 + w) * 32;
  uint32* pFlag  = flags + (dir * 2 + (1 - w)) * 32;
  float* coefD = coef + (size_t)dir * TT * 16;

  const int unit = w * 128 + wv * 16 + lo;  // hidden unit this lane owns
  const int b0 = hi * 4;

  // register-resident weights: wfrag[gate][ktile]
  bf16x8 wfrag[4][8];
#pragma unroll
  for (int gt = 0; gt < 4; ++gt) {
    const float* wrow = Whh + (size_t)(gt * HID + unit) * HID;
#pragma unroll
    for (int kt = 0; kt < 8; ++kt) {
      const float* p = wrow + kt * 32 + hi * 8;
      bf16x8 f;
#pragma unroll
      for (int j = 0; j < 8; ++j) f[j] = (short)f2bf(p[j]);
      wfrag[gt][kt] = f;
    }
  }

  const float cbias = (MODE == 0) ? (dir ? cbB[0] : cbF[0]) : 0.f;

  float hprev[4] = {0, 0, 0, 0}, cprev[4] = {0, 0, 0, 0};
  float xg[4][4];
  float co[4] = {0, 0, 0, 0};

  {
    const int t0 = dir ? (TT - 1) : 0;
#pragma unroll
    for (int r = 0; r < 4; ++r) {
      const ushort* p = xpD + ((size_t)(b0 + r) * TT + t0) * 1024 + unit;
#pragma unroll
      for (int gt = 0; gt < 4; ++gt) xg[gt][r] = bf2f(p[gt * HID]);
    }
  }

  for (int s = 0; s < TT; ++s) {
    // ---- wait for partner's h_{s-1} ----
    if (s > 0) {
      if (wv == 0) {
        while (__hip_atomic_load(pFlag, __ATOMIC_ACQUIRE, __HIP_MEMORY_SCOPE_AGENT) < (uint32)s) {}
      }
      __syncthreads();  // releases other waves; also orders prior-step LDS writes
    }

    // ---- build A-fragments of h_{s-1} ----
    bf16x8 af[8];
    const ushort* hb = hst + (s & 1) * (BATCH * HID);
#pragma unroll
    for (int q = 0; q < 4; ++q) {       // partner half from L3 (agent atomics)
      int kt = (1 - w) * 4 + q;
      const uint32* p = (const uint32*)(hb + lo * HID + kt * 32 + hi * 8);
      union { bf16x8 v; uint32 u[4]; } tmp;
#pragma unroll
      for (int qq = 0; qq < 4; ++qq)
        tmp.u[qq] = __hip_atomic_load(p + qq, __ATOMIC_RELAXED, __HIP_MEMORY_SCOPE_AGENT);
      af[kt] = tmp.v;
    }
#pragma unroll
    for (int q = 0; q < 4; ++q) {       // own half from LDS
      int kt = w * 4 + q;
      int bo = (s & 1) * 4096 + lo * 256 + (kt * 32 + hi * 8 - w * 128) * 2;
      bo ^= ((lo & 7) << 4);
      af[kt] = *(const bf16x8*)((const char*)ldsH + bo);
    }

    // ---- recurrent matvec: own-k tiles first (LDS data arrives first) ----
    f32x4 acc[4] = {};
#pragma unroll
    for (int q = 0; q < 8; ++q) {
      int kt = (q + w * 4) & 7;
#pragma unroll
      for (int gt = 0; gt < 4; ++gt)
        acc[gt] = __builtin_amdgcn_mfma_f32_16x16x32_bf16(af[kt], wfrag[gt][kt], acc[gt], 0, 0, 0);
    }

    // ---- gates ----
#pragma unroll
    for (int r = 0; r < 4; ++r) {
      float gi = acc[0][r] + xg[0][r];
      float gf = acc[1][r] + xg[1][r];
      float gg = acc[2][r] + xg[2][r];
      float go = acc[3][r] + xg[3][r];
      float cn = sigm(gf) * cprev[r] + sigm(gi) * tanh_fast(gg);
      float hn = sigm(go) * tanh_fast(cn) + co[r] * hprev[r];
      cprev[r] = cn; hprev[r] = hn;
    }

    // ---- publish h_s: LDS (own half, swizzled) + global staging (for partner) ----
    {
      ushort* ho = hst + ((s + 1) & 1) * (BATCH * HID);
      int ldsbuf = ((s + 1) & 1) * 4096;
#pragma unroll
      for (int r = 0; r < 4; ++r) {
        uint32 h16 = f2bf(hprev[r]);
        uint32 p16 = (uint32)__shfl_xor((int)h16, 1);
        if (!(lo & 1)) {
          uint32 pk = h16 | (p16 << 16);
          __hip_atomic_store((uint32*)(ho + (b0 + r) * HID + unit), pk,
                             __ATOMIC_RELAXED, __HIP_MEMORY_SCOPE_AGENT);
          int bo = ldsbuf + (b0 + r) * 256 + (wv * 16 + lo) * 2;
          bo ^= (((b0 + r) & 7) << 4);
          *(uint32*)((char*)ldsH + bo) = pk;
        }
      }
    }
    __syncthreads();  // drains vmcnt+lgkmcnt for all waves
    if (tid == 0)
      __hip_atomic_store(myFlag, (uint32)(s + 1), __ATOMIC_RELEASE, __HIP_MEMORY_SCOPE_AGENT);

    // ---- off-critical-path work ----
    // dcg: coeff[s-1] from af (= full h_{s-1}, batch-replicated across waves)
    if (MODE == 0 && s > 0 && wv == 0) {
      float part = 0.f;
#pragma unroll
      for (int kt = 0; kt < 8; ++kt) {
        const float* cwp = &ldsCW[kt * 32 + hi * 8];
        f32x4 c0 = *(const f32x4*)cwp;
        f32x4 c1 = *(const f32x4*)(cwp + 4);
#pragma unroll
        for (int j = 0; j < 4; ++j) {
          part += c0[j] * bf2f((ushort)af[kt][j]);
          part += c1[j] * bf2f((ushort)af[kt][4 + j]);
        }
      }
      part += __shfl_xor(part, 16);
      part += __shfl_xor(part, 32);
      if (w == 0 && hi == 0)
        coefD[(size_t)(s - 1) * 16 + lo] = 0.9f * sigm(part + cbias);
    }

    // outputs
    const int t_nat = dir ? (TT - 1 - s) : s;
    if (MODE == 1) {
#pragma unroll
      for (int r = 0; r < 4; ++r)
        outBf[((size_t)(b0 + r) * TT + t_nat) * 512 + dir * 256 + unit] = f2bf(hprev[r]);
    } else if (MODE == 2) {
#pragma unroll
      for (int r = 0; r < 4; ++r)
        outF32[((size_t)(b0 + r) * TT + t_nat) * 512 + dir * 256 + unit] = hprev[r];
    }

    // prefetch xg and coeff for step s+1
    if (s + 1 < TT) {
      const int tn = dir ? (TT - 2 - s) : (s + 1);
#pragma unroll
      for (int r = 0; r < 4; ++r) {
        const ushort* p = xpD + ((size_t)(b0 + r) * TT + tn) * 1024 + unit;
#pragma unroll
        for (int gt = 0; gt < 4; ++gt) xg[gt][r] = bf2f(p[gt * HID]);
        if (MODE != 0) co[r] = coefD[(size_t)(s + 1) * 16 + (b0 + r)];
      }
    }
  }

  // dcg epilogue: coeff[TT-1] from h_{TT-1}
  if (MODE == 0 && wv == 0 && w == 0) {
    while (__hip_atomic_load(pFlag, __ATOMIC_ACQUIRE, __HIP_MEMORY_SCOPE_AGENT) < (uint32)TT) {}
    bf16x8 af[8];
    const ushort* hb = hst;  // buf (TT&1)==0 holds h_{TT-1}
#pragma unroll
    for (int q = 0; q < 4; ++q) {
      int kt = (1 - w) * 4 + q;
      const uint32* p = (const uint32*)(hb + lo * HID + kt * 32 + hi * 8);
      union { bf16x8 v; uint32 u[4]; } tmp;
#pragma unroll
      for (int qq = 0; qq < 4; ++qq)
        tmp.u[qq] = __hip_atomic_load(p + qq, __ATOMIC_RELAXED, __HIP_MEMORY_SCOPE_AGENT);
      af[kt] = tmp.v;
    }
#pragma unroll
    for (int q = 0; q < 4; ++q) {
      int kt = w * 4 + q;
      int bo = 0 * 4096 + lo * 256 + (kt * 32 + hi * 8 - w * 128) * 2;
      bo ^= ((lo & 7) << 4);
      af[kt] = *(const bf16x8*)((const char*)ldsH + bo);
    }
    float part = 0.f;
#pragma unroll
    for (int kt = 0; kt < 8; ++kt) {
      const float* cwp = &ldsCW[kt * 32 + hi * 8];
      f32x4 c0 = *(const f32x4*)cwp;
      f32x4 c1 = *(const f32x4*)(cwp + 4);
#pragma unroll
      for (int j = 0; j < 4; ++j) {
        part += c0[j] * bf2f((ushort)af[kt][j]);
        part += c1[j] * bf2f((ushort)af[kt][4 + j]);
      }
    }
    part += __shfl_xor(part, 16);
    part += __shfl_xor(part, 32);
    if (hi == 0)
      coefD[(size_t)(TT - 1) * 16 + lo] = 0.9f * sigm(part + cbias);
  }
}

extern "C" void kernel_launch(void* const* d_in, const int* in_sizes, int n_in,
                              void* d_out, int out_size, void* d_ws, size_t ws_size,
                              hipStream_t stream)
{
  const float* x       = (const float*)d_in[0];
  const float* dWih_f  = (const float*)d_in[1];
  const float* dWhh_f  = (const float*)d_in[2];
  const float* dbih_f  = (const float*)d_in[3];
  const float* dbhh_f  = (const float*)d_in[4];
  const float* dWih_b  = (const float*)d_in[5];
  const float* dWhh_b  = (const float*)d_in[6];
  const float* dbih_b  = (const float*)d_in[7];
  const float* dbhh_b  = (const float*)d_in[8];
  const float* l0Wih_f = (const float*)d_in[9];
  const float* l0Whh_f = (const float*)d_in[10];
  const float* l0bih_f = (const float*)d_in[11];
  const float* l0bhh_f = (const float*)d_in[12];
  const float* l0Wih_b = (const float*)d_in[13];
  const float* l0Whh_b = (const float*)d_in[14];
  const float* l0bih_b = (const float*)d_in[15];
  const float* l0bhh_b = (const float*)d_in[16];
  const float* l1Wih_f = (const float*)d_in[17];
  const float* l1Whh_f = (const float*)d_in[18];
  const float* l1bih_f = (const float*)d_in[19];
  const float* l1bhh_f = (const float*)d_in[20];
  const float* l1Wih_b = (const float*)d_in[21];
  const float* l1Whh_b = (const float*)d_in[22];
  const float* l1bih_b = (const float*)d_in[23];
  const float* l1bhh_b = (const float*)d_in[24];
  const float* cw_f    = (const float*)d_in[25];
  const float* cbi_f   = (const float*)d_in[26];
  const float* cw_b    = (const float*)d_in[27];
  const float* cbi_b   = (const float*)d_in[28];

  char* ws = (char*)d_ws;
  constexpr size_t OFF_XP   = 0;
  constexpr size_t SZ_XP    = 2ull * BATCH * TT * 1024 * 2;   // 128 MB
  constexpr size_t OFF_XCAT = OFF_XP + SZ_XP;
  constexpr size_t SZ_XCAT  = (size_t)BATCH * TT * 512 * 2;   // 32 MB
  constexpr size_t OFF_XBF  = OFF_XCAT + SZ_XCAT;
  constexpr size_t SZ_XBF   = (size_t)BATCH * TT * 256 * 2;   // 16 MB
  constexpr size_t OFF_WA   = OFF_XBF + SZ_XBF;
  constexpr size_t SZ_WAB   = 2048ull * 256 * 2;
  constexpr size_t OFF_WB   = OFF_WA + SZ_WAB;
  constexpr size_t OFF_WC   = OFF_WB + SZ_WAB;
  constexpr size_t SZ_WC    = 2048ull * 512 * 2;
  constexpr size_t OFF_BA   = OFF_WC + SZ_WC;
  constexpr size_t OFF_BB   = OFF_BA + 8192;
  constexpr size_t OFF_BC   = OFF_BB + 8192;
  constexpr size_t OFF_CO   = OFF_BC + 8192;
  constexpr size_t SZ_CO    = 2ull * TT * 16 * 4;             // [dir][t][b] fp32
  constexpr size_t OFF_SYNC = OFF_CO + SZ_CO;
  constexpr size_t SZ_HST   = 3ull * 2 * 2 * BATCH * HID * 2; // 3 scans x 32KB
  constexpr size_t SZ_FLG   = 3ull * 128 * 4;                 // 3 scans x 4 flags x 32 uints
  constexpr size_t NEED     = OFF_SYNC + SZ_HST + SZ_FLG;
  if (ws_size < NEED) return;

  ushort* xp    = (ushort*)(ws + OFF_XP);
  ushort* xcat  = (ushort*)(ws + OFF_XCAT);
  ushort* xbf   = (ushort*)(ws + OFF_XBF);
  ushort* wA    = (ushort*)(ws + OFF_WA);
  ushort* wB    = (ushort*)(ws + OFF_WB);
  ushort* wC    = (ushort*)(ws + OFF_WC);
  float*  biasA = (float*)(ws + OFF_BA);
  float*  biasB = (float*)(ws + OFF_BB);
  float*  biasC = (float*)(ws + OFF_BC);
  float*  coef  = (float*)(ws + OFF_CO);
  ushort* hst   = (ushort*)(ws + OFF_SYNC);
  uint32* flg   = (uint32*)(ws + OFF_SYNC + SZ_HST);

  prep_kernel<<<512, 256, 0, stream>>>(
      x, dWih_f, dWih_b, l0Wih_f, l0Wih_b, l1Wih_f, l1Wih_b,
      dbih_f, dbhh_f, dbih_b, dbhh_b, l0bih_f, l0bhh_f, l0bih_b, l0bhh_b,
      l1bih_f, l1bhh_f, l1bih_b, l1bhh_b,
      xbf, wA, wB, wC, biasA, biasB, biasC);
  hipMemsetAsync(ws + OFF_SYNC, 0, SZ_HST + SZ_FLG, stream);

  const int HSTR = 2 * 2 * BATCH * HID;  // ushorts per scan staging

  // phase A: dcg
  gemm_xp<<<dim3(16, 256), 256, 0, stream>>>(xbf, wA, 256, biasA, xp);
  scan2<0><<<4, 512, 0, stream>>>(xp, dWhh_f, dWhh_b, cw_f, cw_b, cbi_f, cbi_b,
                                  coef, hst + 0 * HSTR, flg + 0 * 128,
                                  (ushort*)nullptr, (float*)nullptr);
  // phase B: layer 0
  gemm_xp<<<dim3(16, 256), 256, 0, stream>>>(xbf, wB, 256, biasB, xp);
  scan2<1><<<4, 512, 0, stream>>>(xp, l0Whh_f, l0Whh_b, cw_f, cw_b, cbi_f, cbi_b,
                                  coef, hst + 1 * HSTR, flg + 1 * 128,
                                  xcat, (float*)nullptr);
  // phase C: layer 1
  gemm_xp<<<dim3(16, 256), 256, 0, stream>>>(xcat, wC, 512, biasC, xp);
  scan2<2><<<4, 512, 0, stream>>>(xp, l1Whh_f, l1Whh_b, cw_f, cw_b, cbi_f, cbi_b,
                                  coef, hst + 2 * HSTR, flg + 2 * 128,
                                  (ushort*)nullptr, (float*)d_out);
}

// Round 3
// 39610.464 us; speedup vs baseline: 18.9612x; 18.9612x over previous
//
#include <hip/hip_runtime.h>

typedef unsigned short ushort;
typedef unsigned int uint32;
typedef __attribute__((ext_vector_type(8))) short bf16x8;
typedef __attribute__((ext_vector_type(4))) float f32x4;

#define BATCH 16
#define TT 2048
#define HID 256

__device__ __forceinline__ ushort f2bf(float f) {
  union { float f; uint32 u; } v; v.f = f;
  uint32 r = v.u + 0x7FFFu + ((v.u >> 16) & 1u);
  return (ushort)(r >> 16);
}
__device__ __forceinline__ float bf2f(ushort u) {
  union { uint32 u; float f; } v; v.u = ((uint32)u) << 16; return v.f;
}
__device__ __forceinline__ float sigm(float x) { return 1.0f / (1.0f + __expf(-x)); }
__device__ __forceinline__ float tanh_fast(float x) { return 1.0f - 2.0f / (__expf(2.0f * x) + 1.0f); }

// ---------------- prep: casts + weight concat + bias sums ----------------
__global__ void prep_kernel(
    const float* __restrict__ x,
    const float* __restrict__ dWih_f, const float* __restrict__ dWih_b,
    const float* __restrict__ l0Wih_f, const float* __restrict__ l0Wih_b,
    const float* __restrict__ l1Wih_f, const float* __restrict__ l1Wih_b,
    const float* __restrict__ dbih_f, const float* __restrict__ dbhh_f,
    const float* __restrict__ dbih_b, const float* __restrict__ dbhh_b,
    const float* __restrict__ l0bih_f, const float* __restrict__ l0bhh_f,
    const float* __restrict__ l0bih_b, const float* __restrict__ l0bhh_b,
    const float* __restrict__ l1bih_f, const float* __restrict__ l1bhh_f,
    const float* __restrict__ l1bih_b, const float* __restrict__ l1bhh_b,
    ushort* __restrict__ xbf, ushort* __restrict__ wA, ushort* __restrict__ wB,
    ushort* __restrict__ wC, float* __restrict__ biasA, float* __restrict__ biasB,
    float* __restrict__ biasC)
{
  int g = blockIdx.x * blockDim.x + threadIdx.x;
  int str = gridDim.x * blockDim.x;
  for (int i = g; i < (BATCH * TT * 256) / 4; i += str) {
    float4 v = ((const float4*)x)[i];
    ushort4 o; o.x = f2bf(v.x); o.y = f2bf(v.y); o.z = f2bf(v.z); o.w = f2bf(v.w);
    ((ushort4*)xbf)[i] = o;
  }
  for (int i = g; i < 2048 * 256; i += str)
    wA[i] = f2bf(i < 1024 * 256 ? dWih_f[i] : dWih_b[i - 1024 * 256]);
  for (int i = g; i < 2048 * 256; i += str)
    wB[i] = f2bf(i < 1024 * 256 ? l0Wih_f[i] : l0Wih_b[i - 1024 * 256]);
  for (int i = g; i < 2048 * 512; i += str)
    wC[i] = f2bf(i < 1024 * 512 ? l1Wih_f[i] : l1Wih_b[i - 1024 * 512]);
  for (int i = g; i < 2048; i += str) {
    biasA[i] = i < 1024 ? dbih_f[i] + dbhh_f[i] : dbih_b[i - 1024] + dbhh_b[i - 1024];
    biasB[i] = i < 1024 ? l0bih_f[i] + l0bhh_f[i] : l0bih_b[i - 1024] + l0bhh_b[i - 1024];
    biasC[i] = i < 1024 ? l1bih_f[i] + l1bhh_f[i] : l1bih_b[i - 1024] + l1bhh_b[i - 1024];
  }
}

// ---------------- GEMM: xp = A[32768,K] * B[2048,K]^T + bias, out bf16 ----------------
__global__ __launch_bounds__(256) void gemm_xp(
    const ushort* __restrict__ A, const ushort* __restrict__ B, int K,
    const float* __restrict__ bias, ushort* __restrict__ xp)
{
  __shared__ __align__(16) ushort lA[128 * 64];
  __shared__ __align__(16) ushort lB[128 * 64];
  const int tid = threadIdx.x;
  const int lane = tid & 63, wv = tid >> 6;
  const int lo = lane & 15, hi = lane >> 4;
  const int wr = wv >> 1, wc = wv & 1;
  const int bm = blockIdx.y * 128, bn = blockIdx.x * 128;

  f32x4 acc[4][4] = {};

  const int nk = K >> 6;
  for (int kt = 0; kt < nk; ++kt) {
    uint4 ra[4], rb[4];
#pragma unroll
    for (int i = 0; i < 4; ++i) {
      int slot = i * 256 + tid;
      int r = slot >> 3, c8 = slot & 7;
      ra[i] = *(const uint4*)(A + (size_t)(bm + r) * K + kt * 64 + c8 * 8);
      rb[i] = *(const uint4*)(B + (size_t)(bn + r) * K + kt * 64 + c8 * 8);
    }
    __syncthreads();
#pragma unroll
    for (int i = 0; i < 4; ++i) {
      int slot = i * 256 + tid;
      int r = slot >> 3, c8 = slot & 7;
      int boff = r * 128 + ((c8 ^ (r & 7)) << 4);
      *(uint4*)((char*)lA + boff) = ra[i];
      *(uint4*)((char*)lB + boff) = rb[i];
    }
    __syncthreads();
#pragma unroll
    for (int kk = 0; kk < 2; ++kk) {
      bf16x8 fa[4], fb[4];
#pragma unroll
      for (int mt = 0; mt < 4; ++mt) {
        int r = wr * 64 + mt * 16 + lo;
        int c8 = kk * 4 + hi;
        fa[mt] = *(const bf16x8*)((const char*)lA + r * 128 + ((c8 ^ (r & 7)) << 4));
      }
#pragma unroll
      for (int nt = 0; nt < 4; ++nt) {
        int r = wc * 64 + nt * 16 + lo;
        int c8 = kk * 4 + hi;
        fb[nt] = *(const bf16x8*)((const char*)lB + r * 128 + ((c8 ^ (r & 7)) << 4));
      }
#pragma unroll
      for (int mt = 0; mt < 4; ++mt)
#pragma unroll
        for (int nt = 0; nt < 4; ++nt)
          acc[mt][nt] = __builtin_amdgcn_mfma_f32_16x16x32_bf16(fa[mt], fb[nt], acc[mt][nt], 0, 0, 0);
    }
  }
#pragma unroll
  for (int nt = 0; nt < 4; ++nt) {
    int n = bn + wc * 64 + nt * 16 + lo;
    float bv = bias[n];
#pragma unroll
    for (int mt = 0; mt < 4; ++mt) {
#pragma unroll
      for (int r = 0; r < 4; ++r) {
        float val = acc[mt][nt][r] + bv;
        uint32 h16 = f2bf(val);
        uint32 p16 = (uint32)__shfl_xor((int)h16, 1);
        if (!(lo & 1)) {
          int m = bm + wr * 64 + mt * 16 + hi * 4 + r;
          size_t dst = (size_t)(n >> 10) * ((size_t)BATCH * TT * 1024) + (size_t)m * 1024 + (n & 1023);
          *(uint32*)(xp + dst) = h16 | (p16 << 16);
        }
      }
    }
  }
}

// agent-scope 16B load of h fragment (4 relaxed dword atomics)
__device__ __forceinline__ bf16x8 load_hfrag(const ushort* p) {
  union { bf16x8 v; uint32 u[4]; } t;
#pragma unroll
  for (int j = 0; j < 4; ++j)
    t.u[j] = __hip_atomic_load((const uint32*)p + j, __ATOMIC_RELAXED, __HIP_MEMORY_SCOPE_AGENT);
  return t.v;
}

// ---------------- sequential LSTM scan, v3 (all register indices static) ----------------
// grid = 4 blocks: dir(2) x half(2). 512 thr = 8 waves (2/SIMD).
// Each WG owns 128 hidden units; weights register-resident (static indices!).
// Per step: own h half via LDS (swizzled), partner half via agent atomics.
// Sync: one release-store flag per WG (own cacheline), wave0-only polling.
template <int MODE>
__global__ __launch_bounds__(512, 2) void scan2(
    const ushort* __restrict__ xp,
    const float* __restrict__ WhhF, const float* __restrict__ WhhB,
    const float* __restrict__ cwF, const float* __restrict__ cwB,
    const float* __restrict__ cbF, const float* __restrict__ cbB,
    float* __restrict__ coef,             // [2 dir][TT][16] fp32, scan-step indexed
    ushort* __restrict__ hstage,          // [2 dir][2 buf][16][256] bf16
    uint32* __restrict__ flags,           // [2dir*2wg] stride 32 uints
    ushort* __restrict__ outBf, float* __restrict__ outF32)
{
  const int tid = threadIdx.x;
  const int lane = tid & 63, wv = tid >> 6;
  const int lo = lane & 15, hi = lane >> 4;
  const int dir = blockIdx.x >> 1, w = blockIdx.x & 1;

  __shared__ __align__(16) ushort ldsH[2][16 * 128];  // [buf][b][128 units], XOR-swizzled
  __shared__ float ldsCW[256];

  for (int i = tid; i < 2 * 16 * 128 / 2; i += 512) ((uint32*)ldsH)[i] = 0;
  if (MODE == 0 && tid < 256) ldsCW[tid] = (dir ? cwB : cwF)[tid];
  __syncthreads();

  const ushort* xpD = xp + (size_t)dir * ((size_t)BATCH * TT * 1024);
  const float* Whh = dir ? WhhB : WhhF;
  ushort* hst = hstage + dir * (2 * BATCH * HID);
  uint32* myFlag = flags + (dir * 2 + w) * 32;
  uint32* pFlag  = flags + (dir * 2 + (1 - w)) * 32;
  float* coefD = coef + (size_t)dir * TT * 16;

  const int unit = w * 128 + wv * 16 + lo;  // hidden unit this lane owns
  const int b0 = hi * 4;

  // register-resident weights: wfrag[gate][ktile] — ALL indices compile-time
  bf16x8 wfrag[4][8];
#pragma unroll
  for (int gt = 0; gt < 4; ++gt) {
    const float* wrow = Whh + (size_t)(gt * HID + unit) * HID;
#pragma unroll
    for (int kt = 0; kt < 8; ++kt) {
      const float* p = wrow + kt * 32 + hi * 8;
      bf16x8 f;
#pragma unroll
      for (int j = 0; j < 8; ++j) f[j] = (short)f2bf(p[j]);
      wfrag[gt][kt] = f;
    }
  }

  const float cbias = (MODE == 0) ? (dir ? cbB[0] : cbF[0]) : 0.f;

  float hprev[4] = {0, 0, 0, 0}, cprev[4] = {0, 0, 0, 0};
  float xg[4][4];
  float co[4] = {0, 0, 0, 0};

  {
    const int t0 = dir ? (TT - 1) : 0;
#pragma unroll
    for (int r = 0; r < 4; ++r) {
      const ushort* p = xpD + ((size_t)(b0 + r) * TT + t0) * 1024 + unit;
#pragma unroll
      for (int gt = 0; gt < 4; ++gt) xg[gt][r] = bf2f(p[gt * HID]);
    }
  }

  for (int s = 0; s < TT; ++s) {
    // ---- wait for partner's h_{s-1} ----
    if (s > 0) {
      if (wv == 0) {
        while (__hip_atomic_load(pFlag, __ATOMIC_ACQUIRE, __HIP_MEMORY_SCOPE_AGENT) < (uint32)s) {}
      }
      __syncthreads();  // releases other waves; also orders prior-step LDS writes
    }

    // ---- build A-fragments of h_{s-1}: named regs, static indices ----
    // own half: LDS (local cols 0..127); partner half: global staging (agent).
    bf16x8 af0, af1, af2, af3, af4, af5, af6, af7;
    {
      const ushort* hb = hst + (s & 1) * (BATCH * HID);
      const char* lbase = (const char*)ldsH + (s & 1) * 4096 + lo * 256;
      const int lxor = (lo & 7) << 4;
      if (w == 0) {
        af0 = *(const bf16x8*)(lbase + (((0 * 32 + hi * 8) * 2) ^ lxor));
        af1 = *(const bf16x8*)(lbase + (((1 * 32 + hi * 8) * 2) ^ lxor));
        af2 = *(const bf16x8*)(lbase + (((2 * 32 + hi * 8) * 2) ^ lxor));
        af3 = *(const bf16x8*)(lbase + (((3 * 32 + hi * 8) * 2) ^ lxor));
        const ushort* gb = hb + lo * HID + hi * 8;
        af4 = load_hfrag(gb + 4 * 32);
        af5 = load_hfrag(gb + 5 * 32);
        af6 = load_hfrag(gb + 6 * 32);
        af7 = load_hfrag(gb + 7 * 32);
      } else {
        const ushort* gb = hb + lo * HID + hi * 8;
        af0 = load_hfrag(gb + 0 * 32);
        af1 = load_hfrag(gb + 1 * 32);
        af2 = load_hfrag(gb + 2 * 32);
        af3 = load_hfrag(gb + 3 * 32);
        af4 = *(const bf16x8*)(lbase + (((0 * 32 + hi * 8) * 2) ^ lxor));
        af5 = *(const bf16x8*)(lbase + (((1 * 32 + hi * 8) * 2) ^ lxor));
        af6 = *(const bf16x8*)(lbase + (((2 * 32 + hi * 8) * 2) ^ lxor));
        af7 = *(const bf16x8*)(lbase + (((3 * 32 + hi * 8) * 2) ^ lxor));
      }
    }

    // ---- recurrent matvec: fixed kt order, static indices ----
    f32x4 acc[4] = {};
#pragma unroll
    for (int gt = 0; gt < 4; ++gt) {
      acc[gt] = __builtin_amdgcn_mfma_f32_16x16x32_bf16(af0, wfrag[gt][0], acc[gt], 0, 0, 0);
      acc[gt] = __builtin_amdgcn_mfma_f32_16x16x32_bf16(af1, wfrag[gt][1], acc[gt], 0, 0, 0);
      acc[gt] = __builtin_amdgcn_mfma_f32_16x16x32_bf16(af2, wfrag[gt][2], acc[gt], 0, 0, 0);
      acc[gt] = __builtin_amdgcn_mfma_f32_16x16x32_bf16(af3, wfrag[gt][3], acc[gt], 0, 0, 0);
      acc[gt] = __builtin_amdgcn_mfma_f32_16x16x32_bf16(af4, wfrag[gt][4], acc[gt], 0, 0, 0);
      acc[gt] = __builtin_amdgcn_mfma_f32_16x16x32_bf16(af5, wfrag[gt][5], acc[gt], 0, 0, 0);
      acc[gt] = __builtin_amdgcn_mfma_f32_16x16x32_bf16(af6, wfrag[gt][6], acc[gt], 0, 0, 0);
      acc[gt] = __builtin_amdgcn_mfma_f32_16x16x32_bf16(af7, wfrag[gt][7], acc[gt], 0, 0, 0);
    }

    // ---- gates ----
#pragma unroll
    for (int r = 0; r < 4; ++r) {
      float gi = acc[0][r] + xg[0][r];
      float gf = acc[1][r] + xg[1][r];
      float gg = acc[2][r] + xg[2][r];
      float go = acc[3][r] + xg[3][r];
      float cn = sigm(gf) * cprev[r] + sigm(gi) * tanh_fast(gg);
      float hn = sigm(go) * tanh_fast(cn) + co[r] * hprev[r];
      cprev[r] = cn; hprev[r] = hn;
    }

    // ---- publish h_s: LDS (own half, swizzled) + global staging (for partner) ----
    {
      ushort* ho = hst + ((s + 1) & 1) * (BATCH * HID);
      int ldsbuf = ((s + 1) & 1) * 4096;
#pragma unroll
      for (int r = 0; r < 4; ++r) {
        uint32 h16 = f2bf(hprev[r]);
        uint32 p16 = (uint32)__shfl_xor((int)h16, 1);
        if (!(lo & 1)) {
          uint32 pk = h16 | (p16 << 16);
          __hip_atomic_store((uint32*)(ho + (b0 + r) * HID + unit), pk,
                             __ATOMIC_RELAXED, __HIP_MEMORY_SCOPE_AGENT);
          int bo = ldsbuf + (b0 + r) * 256 + (wv * 16 + lo) * 2;
          bo ^= (((b0 + r) & 7) << 4);
          *(uint32*)((char*)ldsH + bo) = pk;
        }
      }
    }
    __syncthreads();  // drains vmcnt+lgkmcnt for all waves
    if (tid == 0)
      __hip_atomic_store(myFlag, (uint32)(s + 1), __ATOMIC_RELEASE, __HIP_MEMORY_SCOPE_AGENT);

    // ---- off-critical-path work ----
    // dcg: coeff[s-1] from af (= full h_{s-1}, batch-replicated across waves)
    if (MODE == 0 && s > 0 && wv == 0) {
      float part = 0.f;
      const bf16x8 afv[8] = {af0, af1, af2, af3, af4, af5, af6, af7};
#pragma unroll
      for (int kt = 0; kt < 8; ++kt) {
        const float* cwp = &ldsCW[kt * 32 + hi * 8];
        f32x4 c0 = *(const f32x4*)cwp;
        f32x4 c1 = *(const f32x4*)(cwp + 4);
#pragma unroll
        for (int j = 0; j < 4; ++j) {
          part += c0[j] * bf2f((ushort)afv[kt][j]);
          part += c1[j] * bf2f((ushort)afv[kt][4 + j]);
        }
      }
      part += __shfl_xor(part, 16);
      part += __shfl_xor(part, 32);
      if (w == 0 && hi == 0)
        coefD[(size_t)(s - 1) * 16 + lo] = 0.9f * sigm(part + cbias);
    }

    // outputs
    const int t_nat = dir ? (TT - 1 - s) : s;
    if (MODE == 1) {
#pragma unroll
      for (int r = 0; r < 4; ++r)
        outBf[((size_t)(b0 + r) * TT + t_nat) * 512 + dir * 256 + unit] = f2bf(hprev[r]);
    } else if (MODE == 2) {
#pragma unroll
      for (int r = 0; r < 4; ++r)
        outF32[((size_t)(b0 + r) * TT + t_nat) * 512 + dir * 256 + unit] = hprev[r];
    }

    // prefetch xg and coeff for step s+1
    if (s + 1 < TT) {
      const int tn = dir ? (TT - 2 - s) : (s + 1);
#pragma unroll
      for (int r = 0; r < 4; ++r) {
        const ushort* p = xpD + ((size_t)(b0 + r) * TT + tn) * 1024 + unit;
#pragma unroll
        for (int gt = 0; gt < 4; ++gt) xg[gt][r] = bf2f(p[gt * HID]);
        if (MODE != 0) co[r] = coefD[(size_t)(s + 1) * 16 + (b0 + r)];
      }
    }
  }

  // dcg epilogue: coeff[TT-1] from h_{TT-1} (only w==0 blocks; constants for w=0)
  if (MODE == 0 && wv == 0 && w == 0) {
    while (__hip_atomic_load(pFlag, __ATOMIC_ACQUIRE, __HIP_MEMORY_SCOPE_AGENT) < (uint32)TT) {}
    const ushort* hb = hst;  // buf (TT&1)==0 holds h_{TT-1}
    const char* lbase = (const char*)ldsH + 0 * 4096 + lo * 256;
    const int lxor = (lo & 7) << 4;
    bf16x8 e0 = *(const bf16x8*)(lbase + (((0 * 32 + hi * 8) * 2) ^ lxor));
    bf16x8 e1 = *(const bf16x8*)(lbase + (((1 * 32 + hi * 8) * 2) ^ lxor));
    bf16x8 e2 = *(const bf16x8*)(lbase + (((2 * 32 + hi * 8) * 2) ^ lxor));
    bf16x8 e3 = *(const bf16x8*)(lbase + (((3 * 32 + hi * 8) * 2) ^ lxor));
    const ushort* gb = hb + lo * HID + hi * 8;
    bf16x8 e4 = load_hfrag(gb + 4 * 32);
    bf16x8 e5 = load_hfrag(gb + 5 * 32);
    bf16x8 e6 = load_hfrag(gb + 6 * 32);
    bf16x8 e7 = load_hfrag(gb + 7 * 32);
    float part = 0.f;
    const bf16x8 afv[8] = {e0, e1, e2, e3, e4, e5, e6, e7};
#pragma unroll
    for (int kt = 0; kt < 8; ++kt) {
      const float* cwp = &ldsCW[kt * 32 + hi * 8];
      f32x4 c0 = *(const f32x4*)cwp;
      f32x4 c1 = *(const f32x4*)(cwp + 4);
#pragma unroll
      for (int j = 0; j < 4; ++j) {
        part += c0[j] * bf2f((ushort)afv[kt][j]);
        part += c1[j] * bf2f((ushort)afv[kt][4 + j]);
      }
    }
    part += __shfl_xor(part, 16);
    part += __shfl_xor(part, 32);
    if (hi == 0)
      coefD[(size_t)(TT - 1) * 16 + lo] = 0.9f * sigm(part + cbias);
  }
}

extern "C" void kernel_launch(void* const* d_in, const int* in_sizes, int n_in,
                              void* d_out, int out_size, void* d_ws, size_t ws_size,
                              hipStream_t stream)
{
  const float* x       = (const float*)d_in[0];
  const float* dWih_f  = (const float*)d_in[1];
  const float* dWhh_f  = (const float*)d_in[2];
  const float* dbih_f  = (const float*)d_in[3];
  const float* dbhh_f  = (const float*)d_in[4];
  const float* dWih_b  = (const float*)d_in[5];
  const float* dWhh_b  = (const float*)d_in[6];
  const float* dbih_b  = (const float*)d_in[7];
  const float* dbhh_b  = (const float*)d_in[8];
  const float* l0Wih_f = (const float*)d_in[9];
  const float* l0Whh_f = (const float*)d_in[10];
  const float* l0bih_f = (const float*)d_in[11];
  const float* l0bhh_f = (const float*)d_in[12];
  const float* l0Wih_b = (const float*)d_in[13];
  const float* l0Whh_b = (const float*)d_in[14];
  const float* l0bih_b = (const float*)d_in[15];
  const float* l0bhh_b = (const float*)d_in[16];
  const float* l1Wih_f = (const float*)d_in[17];
  const float* l1Whh_f = (const float*)d_in[18];
  const float* l1bih_f = (const float*)d_in[19];
  const float* l1bhh_f = (const float*)d_in[20];
  const float* l1Wih_b = (const float*)d_in[21];
  const float* l1Whh_b = (const float*)d_in[22];
  const float* l1bih_b = (const float*)d_in[23];
  const float* l1bhh_b = (const float*)d_in[24];
  const float* cw_f    = (const float*)d_in[25];
  const float* cbi_f   = (const float*)d_in[26];
  const float* cw_b    = (const float*)d_in[27];
  const float* cbi_b   = (const float*)d_in[28];

  char* ws = (char*)d_ws;
  constexpr size_t OFF_XP   = 0;
  constexpr size_t SZ_XP    = 2ull * BATCH * TT * 1024 * 2;   // 128 MB
  constexpr size_t OFF_XCAT = OFF_XP + SZ_XP;
  constexpr size_t SZ_XCAT  = (size_t)BATCH * TT * 512 * 2;   // 32 MB
  constexpr size_t OFF_XBF  = OFF_XCAT + SZ_XCAT;
  constexpr size_t SZ_XBF   = (size_t)BATCH * TT * 256 * 2;   // 16 MB
  constexpr size_t OFF_WA   = OFF_XBF + SZ_XBF;
  constexpr size_t SZ_WAB   = 2048ull * 256 * 2;
  constexpr size_t OFF_WB   = OFF_WA + SZ_WAB;
  constexpr size_t OFF_WC   = OFF_WB + SZ_WAB;
  constexpr size_t SZ_WC    = 2048ull * 512 * 2;
  constexpr size_t OFF_BA   = OFF_WC + SZ_WC;
  constexpr size_t OFF_BB   = OFF_BA + 8192;
  constexpr size_t OFF_BC   = OFF_BB + 8192;
  constexpr size_t OFF_CO   = OFF_BC + 8192;
  constexpr size_t SZ_CO    = 2ull * TT * 16 * 4;             // [dir][t][b] fp32
  constexpr size_t OFF_SYNC = OFF_CO + SZ_CO;
  constexpr size_t SZ_HST   = 3ull * 2 * 2 * BATCH * HID * 2; // 3 scans x 32KB
  constexpr size_t SZ_FLG   = 3ull * 128 * 4;                 // 3 scans x 4 flags x 32 uints
  constexpr size_t NEED     = OFF_SYNC + SZ_HST + SZ_FLG;
  if (ws_size < NEED) return;

  ushort* xp    = (ushort*)(ws + OFF_XP);
  ushort* xcat  = (ushort*)(ws + OFF_XCAT);
  ushort* xbf   = (ushort*)(ws + OFF_XBF);
  ushort* wA    = (ushort*)(ws + OFF_WA);
  ushort* wB    = (ushort*)(ws + OFF_WB);
  ushort* wC    = (ushort*)(ws + OFF_WC);
  float*  biasA = (float*)(ws + OFF_BA);
  float*  biasB = (float*)(ws + OFF_BB);
  float*  biasC = (float*)(ws + OFF_BC);
  float*  coef  = (float*)(ws + OFF_CO);
  ushort* hst   = (ushort*)(ws + OFF_SYNC);
  uint32* flg   = (uint32*)(ws + OFF_SYNC + SZ_HST);

  prep_kernel<<<512, 256, 0, stream>>>(
      x, dWih_f, dWih_b, l0Wih_f, l0Wih_b, l1Wih_f, l1Wih_b,
      dbih_f, dbhh_f, dbih_b, dbhh_b, l0bih_f, l0bhh_f, l0bih_b, l0bhh_b,
      l1bih_f, l1bhh_f, l1bih_b, l1bhh_b,
      xbf, wA, wB, wC, biasA, biasB, biasC);
  hipMemsetAsync(ws + OFF_SYNC, 0, SZ_HST + SZ_FLG, stream);

  const int HSTR = 2 * 2 * BATCH * HID;  // ushorts per scan staging

  // phase A: dcg
  gemm_xp<<<dim3(16, 256), 256, 0, stream>>>(xbf, wA, 256, biasA, xp);
  scan2<0><<<4, 512, 0, stream>>>(xp, dWhh_f, dWhh_b, cw_f, cw_b, cbi_f, cbi_b,
                                  coef, hst + 0 * HSTR, flg + 0 * 128,
                                  (ushort*)nullptr, (float*)nullptr);
  // phase B: layer 0
  gemm_xp<<<dim3(16, 256), 256, 0, stream>>>(xbf, wB, 256, biasB, xp);
  scan2<1><<<4, 512, 0, stream>>>(xp, l0Whh_f, l0Whh_b, cw_f, cw_b, cbi_f, cbi_b,
                                  coef, hst + 1 * HSTR, flg + 1 * 128,
                                  xcat, (float*)nullptr);
  // phase C: layer 1
  gemm_xp<<<dim3(16, 256), 256, 0, stream>>>(xcat, wC, 512, biasC, xp);
  scan2<2><<<4, 512, 0, stream>>>(xp, l1Whh_f, l1Whh_b, cw_f, cw_b, cbi_f, cbi_b,
                                  coef, hst + 2 * HSTR, flg + 2 * 128,
                                  (ushort*)nullptr, (float*)d_out);
}

// Round 4
// 26559.274 us; speedup vs baseline: 28.2787x; 1.4914x over previous
//
#include <hip/hip_runtime.h>

typedef unsigned short ushort;
typedef unsigned int uint32;
typedef unsigned long long ull;
typedef __attribute__((ext_vector_type(8))) short bf16x8;
typedef __attribute__((ext_vector_type(4))) float f32x4;

#define BATCH 16
#define TT 2048
#define HID 256

__device__ __forceinline__ ushort f2bf(float f) {
  union { float f; uint32 u; } v; v.f = f;
  uint32 r = v.u + 0x7FFFu + ((v.u >> 16) & 1u);
  return (ushort)(r >> 16);
}
__device__ __forceinline__ float bf2f(ushort u) {
  union { uint32 u; float f; } v; v.u = ((uint32)u) << 16; return v.f;
}
__device__ __forceinline__ float sigm(float x) { return 1.0f / (1.0f + __expf(-x)); }
__device__ __forceinline__ float tanh_fast(float x) { return 1.0f - 2.0f / (__expf(2.0f * x) + 1.0f); }

// ---------------- prep: casts + weight concat + bias sums ----------------
__global__ void prep_kernel(
    const float* __restrict__ x,
    const float* __restrict__ dWih_f, const float* __restrict__ dWih_b,
    const float* __restrict__ l0Wih_f, const float* __restrict__ l0Wih_b,
    const float* __restrict__ l1Wih_f, const float* __restrict__ l1Wih_b,
    const float* __restrict__ dbih_f, const float* __restrict__ dbhh_f,
    const float* __restrict__ dbih_b, const float* __restrict__ dbhh_b,
    const float* __restrict__ l0bih_f, const float* __restrict__ l0bhh_f,
    const float* __restrict__ l0bih_b, const float* __restrict__ l0bhh_b,
    const float* __restrict__ l1bih_f, const float* __restrict__ l1bhh_f,
    const float* __restrict__ l1bih_b, const float* __restrict__ l1bhh_b,
    ushort* __restrict__ xbf, ushort* __restrict__ wA, ushort* __restrict__ wB,
    ushort* __restrict__ wC, float* __restrict__ biasA, float* __restrict__ biasB,
    float* __restrict__ biasC)
{
  int g = blockIdx.x * blockDim.x + threadIdx.x;
  int str = gridDim.x * blockDim.x;
  for (int i = g; i < (BATCH * TT * 256) / 4; i += str) {
    float4 v = ((const float4*)x)[i];
    ushort4 o; o.x = f2bf(v.x); o.y = f2bf(v.y); o.z = f2bf(v.z); o.w = f2bf(v.w);
    ((ushort4*)xbf)[i] = o;
  }
  for (int i = g; i < 2048 * 256; i += str)
    wA[i] = f2bf(i < 1024 * 256 ? dWih_f[i] : dWih_b[i - 1024 * 256]);
  for (int i = g; i < 2048 * 256; i += str)
    wB[i] = f2bf(i < 1024 * 256 ? l0Wih_f[i] : l0Wih_b[i - 1024 * 256]);
  for (int i = g; i < 2048 * 512; i += str)
    wC[i] = f2bf(i < 1024 * 512 ? l1Wih_f[i] : l1Wih_b[i - 1024 * 512]);
  for (int i = g; i < 2048; i += str) {
    biasA[i] = i < 1024 ? dbih_f[i] + dbhh_f[i] : dbih_b[i - 1024] + dbhh_b[i - 1024];
    biasB[i] = i < 1024 ? l0bih_f[i] + l0bhh_f[i] : l0bih_b[i - 1024] + l0bhh_b[i - 1024];
    biasC[i] = i < 1024 ? l1bih_f[i] + l1bhh_f[i] : l1bih_b[i - 1024] + l1bhh_b[i - 1024];
  }
}

// ---------------- GEMM: xp = A[32768,K] * B[2048,K]^T + bias ----------------
// Output layout (per dir): [b][t][pair u/2][gate 0..3][2 units]  (ushort)
__global__ __launch_bounds__(256) void gemm_xp(
    const ushort* __restrict__ A, const ushort* __restrict__ B, int K,
    const float* __restrict__ bias, ushort* __restrict__ xp)
{
  __shared__ __align__(16) ushort lA[128 * 64];
  __shared__ __align__(16) ushort lB[128 * 64];
  const int tid = threadIdx.x;
  const int lane = tid & 63, wv = tid >> 6;
  const int lo = lane & 15, hi = lane >> 4;
  const int wr = wv >> 1, wc = wv & 1;
  const int bm = blockIdx.y * 128, bn = blockIdx.x * 128;

  f32x4 acc[4][4] = {};

  const int nk = K >> 6;
  for (int kt = 0; kt < nk; ++kt) {
    uint4 ra[4], rb[4];
#pragma unroll
    for (int i = 0; i < 4; ++i) {
      int slot = i * 256 + tid;
      int r = slot >> 3, c8 = slot & 7;
      ra[i] = *(const uint4*)(A + (size_t)(bm + r) * K + kt * 64 + c8 * 8);
      rb[i] = *(const uint4*)(B + (size_t)(bn + r) * K + kt * 64 + c8 * 8);
    }
    __syncthreads();
#pragma unroll
    for (int i = 0; i < 4; ++i) {
      int slot = i * 256 + tid;
      int r = slot >> 3, c8 = slot & 7;
      int boff = r * 128 + ((c8 ^ (r & 7)) << 4);
      *(uint4*)((char*)lA + boff) = ra[i];
      *(uint4*)((char*)lB + boff) = rb[i];
    }
    __syncthreads();
#pragma unroll
    for (int kk = 0; kk < 2; ++kk) {
      bf16x8 fa[4], fb[4];
#pragma unroll
      for (int mt = 0; mt < 4; ++mt) {
        int r = wr * 64 + mt * 16 + lo;
        int c8 = kk * 4 + hi;
        fa[mt] = *(const bf16x8*)((const char*)lA + r * 128 + ((c8 ^ (r & 7)) << 4));
      }
#pragma unroll
      for (int nt = 0; nt < 4; ++nt) {
        int r = wc * 64 + nt * 16 + lo;
        int c8 = kk * 4 + hi;
        fb[nt] = *(const bf16x8*)((const char*)lB + r * 128 + ((c8 ^ (r & 7)) << 4));
      }
#pragma unroll
      for (int mt = 0; mt < 4; ++mt)
#pragma unroll
        for (int nt = 0; nt < 4; ++nt)
          acc[mt][nt] = __builtin_amdgcn_mfma_f32_16x16x32_bf16(fa[mt], fb[nt], acc[mt][nt], 0, 0, 0);
    }
  }
#pragma unroll
  for (int nt = 0; nt < 4; ++nt) {
    int n = bn + wc * 64 + nt * 16 + lo;
    float bv = bias[n];
    int dirn = n >> 10;
    int c = n & 1023;
    int gate = c >> 8;
    int u = c & 255;
    size_t base = (size_t)dirn * ((size_t)BATCH * TT * 1024) + (size_t)(u >> 1) * 8 + gate * 2;
#pragma unroll
    for (int mt = 0; mt < 4; ++mt) {
#pragma unroll
      for (int r = 0; r < 4; ++r) {
        float val = acc[mt][nt][r] + bv;
        uint32 h16 = f2bf(val);
        uint32 p16 = (uint32)__shfl_xor((int)h16, 1);
        if (!(lo & 1)) {
          int m = bm + wr * 64 + mt * 16 + hi * 4 + r;
          *(uint32*)(xp + base + (size_t)m * 1024) = h16 | (p16 << 16);
        }
      }
    }
  }
}

// ---------------- sequential LSTM scan, v4: tagged-word exchange ----------------
// grid = 8 blocks: dir(2) x quarter(4). 256 thr = 4 waves, 1 wave/SIMD (512 VGPR cap).
// Each block owns 64 hidden units; weights register-resident, static indices.
// h exchange: per-8B tagged words {tag=s+1 | 2xbf16} in global staging, relaxed
// agent atomics only. The tag IS the sync — no flags, no fences, no barriers.
// Staging layout per dir per buf: ull[128 pair][16 batch].
template <int MODE>
__global__ __launch_bounds__(256, 1) void scan3(
    const ushort* __restrict__ xp,
    const float* __restrict__ WhhF, const float* __restrict__ WhhB,
    const float* __restrict__ cwF, const float* __restrict__ cwB,
    const float* __restrict__ cbF, const float* __restrict__ cbB,
    float* __restrict__ coef,             // [2 dir][TT][16] fp32
    ull* __restrict__ hstage,             // [2 dir][2 buf][128][16] tagged
    ushort* __restrict__ outBf, float* __restrict__ outF32)
{
  const int tid = threadIdx.x;
  const int lane = tid & 63, wv = tid >> 6;      // wv 0..3
  const int lo = lane & 15, hi = lane >> 4;
  const int dir = blockIdx.x >> 2, w = blockIdx.x & 3;  // quarter

  __shared__ float ldsCW[256];
  if (MODE == 0) ldsCW[tid] = (dir ? cwB : cwF)[tid];
  __syncthreads();

  const ushort* xpD = xp + (size_t)dir * ((size_t)BATCH * TT * 1024);
  const float* Whh = dir ? WhhB : WhhF;
  ull* hst = hstage + dir * (2 * 2048);
  float* coefD = coef + (size_t)dir * TT * 16;

  const int unit = w * 64 + wv * 16 + lo;   // hidden unit this lane owns (output col)
  const int b0 = hi * 4;                    // batches b0..b0+3 (output rows)
  const int half = unit & 1;
  const int sh = half * 16;

  // register-resident weights (B-frags): wfrag[gate][kt], all indices static
  bf16x8 wfrag[4][8];
#pragma unroll
  for (int gt = 0; gt < 4; ++gt) {
    const float* wrow = Whh + (size_t)(gt * HID + unit) * HID;
#pragma unroll
    for (int kt = 0; kt < 8; ++kt) {
      const float* p = wrow + kt * 32 + hi * 8;
      bf16x8 f;
#pragma unroll
      for (int j = 0; j < 8; ++j) f[j] = (short)f2bf(p[j]);
      wfrag[gt][kt] = f;
    }
  }

  const float cbias = (MODE == 0) ? (dir ? cbB[0] : cbF[0]) : 0.f;

  float hprev[4] = {0, 0, 0, 0}, cprev[4] = {0, 0, 0, 0};
  float co[4] = {0, 0, 0, 0};
  uint4 xq0, xq1, xq2, xq3;  // raw xp words, one per batch r; convert at use

  {
    const int t0 = dir ? (TT - 1) : 0;
    const size_t pofs = (size_t)(unit >> 1) * 8;
    xq0 = *(const uint4*)(xpD + ((size_t)(b0 + 0) * TT + t0) * 1024 + pofs);
    xq1 = *(const uint4*)(xpD + ((size_t)(b0 + 1) * TT + t0) * 1024 + pofs);
    xq2 = *(const uint4*)(xpD + ((size_t)(b0 + 2) * TT + t0) * 1024 + pofs);
    xq3 = *(const uint4*)(xpD + ((size_t)(b0 + 3) * TT + t0) * 1024 + pofs);
  }

  bf16x8 af[8];  // A-frags of h_{s-1}; only compile-time indices ever used

  for (int s = 0; s < TT; ++s) {
    // convert this step's xg from raw words (loaded a full step ago; no stall)
    float xgi[4], xgf[4], xgg[4], xgo[4];
#define XEXT(Q, R) \
    xgi[R] = bf2f((ushort)(Q.x >> sh)); xgf[R] = bf2f((ushort)(Q.y >> sh)); \
    xgg[R] = bf2f((ushort)(Q.z >> sh)); xgo[R] = bf2f((ushort)(Q.w >> sh));
    XEXT(xq0, 0) XEXT(xq1, 1) XEXT(xq2, 2) XEXT(xq3, 3)
#undef XEXT

    f32x4 acc[4] = {};
    if (s > 0) {
      // poll tagged words of h_{s-1} (tag == s) in buf[s&1]; data rides along
      const ull* bp = hst + (s & 1) * 2048 + hi * 64 + lo;
      const uint32 su = (uint32)s;
      while (true) {
        uint32 bad = 0;
#pragma unroll
        for (int kt = 0; kt < 8; ++kt) {
          ull w0 = __hip_atomic_load(bp + kt * 256 +  0, __ATOMIC_RELAXED, __HIP_MEMORY_SCOPE_AGENT);
          ull w1 = __hip_atomic_load(bp + kt * 256 + 16, __ATOMIC_RELAXED, __HIP_MEMORY_SCOPE_AGENT);
          ull w2 = __hip_atomic_load(bp + kt * 256 + 32, __ATOMIC_RELAXED, __HIP_MEMORY_SCOPE_AGENT);
          ull w3 = __hip_atomic_load(bp + kt * 256 + 48, __ATOMIC_RELAXED, __HIP_MEMORY_SCOPE_AGENT);
          union { bf16x8 v; uint32 d[4]; } t;
          t.d[0] = (uint32)w0; t.d[1] = (uint32)w1; t.d[2] = (uint32)w2; t.d[3] = (uint32)w3;
          af[kt] = t.v;
          bad |= ((uint32)(w0 >> 32)) ^ su; bad |= ((uint32)(w1 >> 32)) ^ su;
          bad |= ((uint32)(w2 >> 32)) ^ su; bad |= ((uint32)(w3 >> 32)) ^ su;
        }
        if (__all(bad == 0)) break;
      }
#pragma unroll
      for (int gt = 0; gt < 4; ++gt) {
        acc[gt] = __builtin_amdgcn_mfma_f32_16x16x32_bf16(af[0], wfrag[gt][0], acc[gt], 0, 0, 0);
        acc[gt] = __builtin_amdgcn_mfma_f32_16x16x32_bf16(af[1], wfrag[gt][1], acc[gt], 0, 0, 0);
        acc[gt] = __builtin_amdgcn_mfma_f32_16x16x32_bf16(af[2], wfrag[gt][2], acc[gt], 0, 0, 0);
        acc[gt] = __builtin_amdgcn_mfma_f32_16x16x32_bf16(af[3], wfrag[gt][3], acc[gt], 0, 0, 0);
        acc[gt] = __builtin_amdgcn_mfma_f32_16x16x32_bf16(af[4], wfrag[gt][4], acc[gt], 0, 0, 0);
        acc[gt] = __builtin_amdgcn_mfma_f32_16x16x32_bf16(af[5], wfrag[gt][5], acc[gt], 0, 0, 0);
        acc[gt] = __builtin_amdgcn_mfma_f32_16x16x32_bf16(af[6], wfrag[gt][6], acc[gt], 0, 0, 0);
        acc[gt] = __builtin_amdgcn_mfma_f32_16x16x32_bf16(af[7], wfrag[gt][7], acc[gt], 0, 0, 0);
      }
    }

    // gates
#pragma unroll
    for (int r = 0; r < 4; ++r) {
      float gi = acc[0][r] + xgi[r];
      float gf = acc[1][r] + xgf[r];
      float gg = acc[2][r] + xgg[r];
      float go = acc[3][r] + xgo[r];
      float cn = sigm(gf) * cprev[r] + sigm(gi) * tanh_fast(gg);
      float hn = sigm(go) * tanh_fast(cn) + co[r] * hprev[r];
      cprev[r] = cn; hprev[r] = hn;
    }

    // publish h_s as tagged words into buf[(s+1)&1]; fire-and-forget
    {
      ull* so = hst + ((s + 1) & 1) * 2048 + (size_t)(w * 32 + wv * 8 + (lo >> 1)) * 16 + b0;
      const ull tg = ((ull)(uint32)(s + 1)) << 32;
#pragma unroll
      for (int r = 0; r < 4; ++r) {
        uint32 h16 = f2bf(hprev[r]);
        uint32 p16 = (uint32)__shfl_xor((int)h16, 1);
        if (!(lo & 1))
          __hip_atomic_store(so + r, (ull)(h16 | (p16 << 16)) | tg,
                             __ATOMIC_RELAXED, __HIP_MEMORY_SCOPE_AGENT);
      }
      asm volatile("" ::: "memory");  // don't let publish sink past the next poll
    }

    // ---- off-critical-path ----
    if (MODE == 0 && s > 0 && w == 0 && wv == 0) {
      float part = 0.f;
#pragma unroll
      for (int kt = 0; kt < 8; ++kt) {
        const float* cwp = &ldsCW[kt * 32 + hi * 8];
        f32x4 c0 = *(const f32x4*)cwp;
        f32x4 c1 = *(const f32x4*)(cwp + 4);
#pragma unroll
        for (int j = 0; j < 4; ++j) {
          part += c0[j] * bf2f((ushort)af[kt][j]);
          part += c1[j] * bf2f((ushort)af[kt][4 + j]);
        }
      }
      part += __shfl_xor(part, 16);
      part += __shfl_xor(part, 32);
      if (hi == 0)
        coefD[(size_t)(s - 1) * 16 + lo] = 0.9f * sigm(part + cbias);
    }

    const int t_nat = dir ? (TT - 1 - s) : s;
    if (MODE == 1) {
#pragma unroll
      for (int r = 0; r < 4; ++r)
        outBf[((size_t)(b0 + r) * TT + t_nat) * 512 + dir * 256 + unit] = f2bf(hprev[r]);
    } else if (MODE == 2) {
#pragma unroll
      for (int r = 0; r < 4; ++r)
        outF32[((size_t)(b0 + r) * TT + t_nat) * 512 + dir * 256 + unit] = hprev[r];
    }

    // prefetch next step's raw xp words + coeff
    if (s + 1 < TT) {
      const int tn = dir ? (TT - 2 - s) : (s + 1);
      const size_t pofs = (size_t)(unit >> 1) * 8;
      xq0 = *(const uint4*)(xpD + ((size_t)(b0 + 0) * TT + tn) * 1024 + pofs);
      xq1 = *(const uint4*)(xpD + ((size_t)(b0 + 1) * TT + tn) * 1024 + pofs);
      xq2 = *(const uint4*)(xpD + ((size_t)(b0 + 2) * TT + tn) * 1024 + pofs);
      xq3 = *(const uint4*)(xpD + ((size_t)(b0 + 3) * TT + tn) * 1024 + pofs);
      if (MODE != 0) {
        co[0] = coefD[(size_t)(s + 1) * 16 + b0 + 0];
        co[1] = coefD[(size_t)(s + 1) * 16 + b0 + 1];
        co[2] = coefD[(size_t)(s + 1) * 16 + b0 + 2];
        co[3] = coefD[(size_t)(s + 1) * 16 + b0 + 3];
      }
    }
  }

  // dcg epilogue: coeff[TT-1] from h_{TT-1} (tag TT, buf[TT&1]==buf[0])
  if (MODE == 0 && w == 0 && wv == 0) {
    const ull* bp = hst + (TT & 1) * 2048 + hi * 64 + lo;
    const uint32 su = (uint32)TT;
    while (true) {
      uint32 bad = 0;
#pragma unroll
      for (int kt = 0; kt < 8; ++kt) {
        ull w0 = __hip_atomic_load(bp + kt * 256 +  0, __ATOMIC_RELAXED, __HIP_MEMORY_SCOPE_AGENT);
        ull w1 = __hip_atomic_load(bp + kt * 256 + 16, __ATOMIC_RELAXED, __HIP_MEMORY_SCOPE_AGENT);
        ull w2 = __hip_atomic_load(bp + kt * 256 + 32, __ATOMIC_RELAXED, __HIP_MEMORY_SCOPE_AGENT);
        ull w3 = __hip_atomic_load(bp + kt * 256 + 48, __ATOMIC_RELAXED, __HIP_MEMORY_SCOPE_AGENT);
        union { bf16x8 v; uint32 d[4]; } t;
        t.d[0] = (uint32)w0; t.d[1] = (uint32)w1; t.d[2] = (uint32)w2; t.d[3] = (uint32)w3;
        af[kt] = t.v;
        bad |= ((uint32)(w0 >> 32)) ^ su; bad |= ((uint32)(w1 >> 32)) ^ su;
        bad |= ((uint32)(w2 >> 32)) ^ su; bad |= ((uint32)(w3 >> 32)) ^ su;
      }
      if (__all(bad == 0)) break;
    }
    float part = 0.f;
#pragma unroll
    for (int kt = 0; kt < 8; ++kt) {
      const float* cwp = &ldsCW[kt * 32 + hi * 8];
      f32x4 c0 = *(const f32x4*)cwp;
      f32x4 c1 = *(const f32x4*)(cwp + 4);
#pragma unroll
      for (int j = 0; j < 4; ++j) {
        part += c0[j] * bf2f((ushort)af[kt][j]);
        part += c1[j] * bf2f((ushort)af[kt][4 + j]);
      }
    }
    part += __shfl_xor(part, 16);
    part += __shfl_xor(part, 32);
    if (hi == 0)
      coefD[(size_t)(TT - 1) * 16 + lo] = 0.9f * sigm(part + cbias);
  }
}

extern "C" void kernel_launch(void* const* d_in, const int* in_sizes, int n_in,
                              void* d_out, int out_size, void* d_ws, size_t ws_size,
                              hipStream_t stream)
{
  const float* x       = (const float*)d_in[0];
  const float* dWih_f  = (const float*)d_in[1];
  const float* dWhh_f  = (const float*)d_in[2];
  const float* dbih_f  = (const float*)d_in[3];
  const float* dbhh_f  = (const float*)d_in[4];
  const float* dWih_b  = (const float*)d_in[5];
  const float* dWhh_b  = (const float*)d_in[6];
  const float* dbih_b  = (const float*)d_in[7];
  const float* dbhh_b  = (const float*)d_in[8];
  const float* l0Wih_f = (const float*)d_in[9];
  const float* l0Whh_f = (const float*)d_in[10];
  const float* l0bih_f = (const float*)d_in[11];
  const float* l0bhh_f = (const float*)d_in[12];
  const float* l0Wih_b = (const float*)d_in[13];
  const float* l0Whh_b = (const float*)d_in[14];
  const float* l0bih_b = (const float*)d_in[15];
  const float* l0bhh_b = (const float*)d_in[16];
  const float* l1Wih_f = (const float*)d_in[17];
  const float* l1Whh_f = (const float*)d_in[18];
  const float* l1bih_f = (const float*)d_in[19];
  const float* l1bhh_f = (const float*)d_in[20];
  const float* l1Wih_b = (const float*)d_in[21];
  const float* l1Whh_b = (const float*)d_in[22];
  const float* l1bih_b = (const float*)d_in[23];
  const float* l1bhh_b = (const float*)d_in[24];
  const float* cw_f    = (const float*)d_in[25];
  const float* cbi_f   = (const float*)d_in[26];
  const float* cw_b    = (const float*)d_in[27];
  const float* cbi_b   = (const float*)d_in[28];

  char* ws = (char*)d_ws;
  constexpr size_t OFF_XP   = 0;
  constexpr size_t SZ_XP    = 2ull * BATCH * TT * 1024 * 2;   // 128 MB
  constexpr size_t OFF_XCAT = OFF_XP + SZ_XP;
  constexpr size_t SZ_XCAT  = (size_t)BATCH * TT * 512 * 2;   // 32 MB
  constexpr size_t OFF_XBF  = OFF_XCAT + SZ_XCAT;
  constexpr size_t SZ_XBF   = (size_t)BATCH * TT * 256 * 2;   // 16 MB
  constexpr size_t OFF_WA   = OFF_XBF + SZ_XBF;
  constexpr size_t SZ_WAB   = 2048ull * 256 * 2;
  constexpr size_t OFF_WB   = OFF_WA + SZ_WAB;
  constexpr size_t OFF_WC   = OFF_WB + SZ_WAB;
  constexpr size_t SZ_WC    = 2048ull * 512 * 2;
  constexpr size_t OFF_BA   = OFF_WC + SZ_WC;
  constexpr size_t OFF_BB   = OFF_BA + 8192;
  constexpr size_t OFF_BC   = OFF_BB + 8192;
  constexpr size_t OFF_CO   = OFF_BC + 8192;
  constexpr size_t SZ_CO    = 2ull * TT * 16 * 4;             // [dir][t][b] fp32
  constexpr size_t OFF_HST  = OFF_CO + SZ_CO;
  constexpr size_t SZ_HST   = 3ull * 2 * 2 * 2048 * 8;        // 3 scans x 64KB tagged
  constexpr size_t NEED     = OFF_HST + SZ_HST;
  if (ws_size < NEED) return;

  ushort* xp    = (ushort*)(ws + OFF_XP);
  ushort* xcat  = (ushort*)(ws + OFF_XCAT);
  ushort* xbf   = (ushort*)(ws + OFF_XBF);
  ushort* wA    = (ushort*)(ws + OFF_WA);
  ushort* wB    = (ushort*)(ws + OFF_WB);
  ushort* wC    = (ushort*)(ws + OFF_WC);
  float*  biasA = (float*)(ws + OFF_BA);
  float*  biasB = (float*)(ws + OFF_BB);
  float*  biasC = (float*)(ws + OFF_BC);
  float*  coef  = (float*)(ws + OFF_CO);
  ull*    hst   = (ull*)(ws + OFF_HST);

  prep_kernel<<<512, 256, 0, stream>>>(
      x, dWih_f, dWih_b, l0Wih_f, l0Wih_b, l1Wih_f, l1Wih_b,
      dbih_f, dbhh_f, dbih_b, dbhh_b, l0bih_f, l0bhh_f, l0bih_b, l0bhh_b,
      l1bih_f, l1bhh_f, l1bih_b, l1bhh_b,
      xbf, wA, wB, wC, biasA, biasB, biasC);
  hipMemsetAsync(ws + OFF_HST, 0, SZ_HST, stream);  // clear stale tags (graph replays!)

  const size_t HSTR = 2 * 2 * 2048;  // ull words per scan

  // phase A: dcg
  gemm_xp<<<dim3(16, 256), 256, 0, stream>>>(xbf, wA, 256, biasA, xp);
  scan3<0><<<8, 256, 0, stream>>>(xp, dWhh_f, dWhh_b, cw_f, cw_b, cbi_f, cbi_b,
                                  coef, hst + 0 * HSTR, (ushort*)nullptr, (float*)nullptr);
  // phase B: layer 0
  gemm_xp<<<dim3(16, 256), 256, 0, stream>>>(xbf, wB, 256, biasB, xp);
  scan3<1><<<8, 256, 0, stream>>>(xp, l0Whh_f, l0Whh_b, cw_f, cw_b, cbi_f, cbi_b,
                                  coef, hst + 1 * HSTR, xcat, (float*)nullptr);
  // phase C: layer 1
  gemm_xp<<<dim3(16, 256), 256, 0, stream>>>(xcat, wC, 512, biasC, xp);
  scan3<2><<<8, 256, 0, stream>>>(xp, l1Whh_f, l1Whh_b, cw_f, cw_b, cbi_f, cbi_b,
                                  coef, hst + 2 * HSTR, (ushort*)nullptr, (float*)d_out);
}